// Round 2
// baseline (591.038 us; speedup 1.0000x reference)
//
#include <hip/hip_runtime.h>

typedef float v2f __attribute__((ext_vector_type(2)));

constexpr int BN   = 131072;   // points
constexpr int HID  = 20;       // hidden width
constexpr int NLAY = 7;        // hidden->hidden layers

// LDS layout (floats)
constexpr int OFF_WH   = 0;      // 7*20*20 = 2800
constexpr int OFF_BH   = 2800;   // 7*20    = 140
constexpr int OFF_WIN  = 2940;   // 3*20    = 60
constexpr int OFF_BIN  = 3000;   // 20
constexpr int OFF_WOUT = 3020;   // 20*2    = 40
constexpr int OFF_BOUT = 3060;   // 2
constexpr int LDS_TOT  = 3064;

__device__ __forceinline__ float fast_tanh(float a) {
    float e = __builtin_amdgcn_exp2f(a * 2.8853900817779268f);
    float r = __builtin_amdgcn_rcpf(e + 1.0f);
    return __builtin_fmaf(-2.0f, r, 1.0f);
}
__device__ __forceinline__ v2f tanh2(v2f a) {
    v2f r; r.x = fast_tanh(a.x); r.y = fast_tanh(a.y); return r;
}

__device__ __forceinline__ void stage_weights(
    float* smem, const float* Win, const float* bin, const float* Wh,
    const float* bh, const float* Wout, const float* bout)
{
    const int tid = threadIdx.x;
    for (int i = tid; i < 2800; i += 256) smem[OFF_WH + i] = Wh[i];
    for (int i = tid; i < 140;  i += 256) smem[OFF_BH + i] = bh[i];
    if (tid < 60) smem[OFF_WIN  + tid] = Win[tid];
    if (tid < 20) smem[OFF_BIN  + tid] = bin[tid];
    if (tid < 40) smem[OFF_WOUT + tid] = Wout[tid];
    if (tid < 2)  smem[OFF_BOUT + tid] = bout[tid];
    __syncthreads();
}

// In-place channel matvec: H (10 x v2f = 20 neurons) <- W^T H (+ bias).
// Channel-diagonal linear layer => only 20 acc regs live beyond state.
template<bool BIASED>
__device__ __forceinline__ void matvec(v2f (&H)[10], const float* __restrict__ Wl,
                                       const float* __restrict__ bl)
{
    v2f acc[10];
    #pragma unroll
    for (int j = 0; j < 10; ++j) {
        if (BIASED) acc[j] = *(const v2f*)&bl[2 * j];
        else        { acc[j].x = 0.f; acc[j].y = 0.f; }
    }
    #pragma unroll
    for (int j = 0; j < 10; ++j) {          // input-neuron pair (2j, 2j+1)
        const float ha = H[j].x, hb = H[j].y;
        const v2f ha2 = {ha, ha}, hb2 = {hb, hb};
        const float* r0 = &Wl[(2 * j) * HID];
        const float* r1 = &Wl[(2 * j + 1) * HID];
        #pragma unroll
        for (int ob = 0; ob < 5; ++ob) {
            float4 w0 = *(const float4*)&r0[4 * ob];
            float4 w1 = *(const float4*)&r1[4 * ob];
            v2f w0a = {w0.x, w0.y}, w0b = {w0.z, w0.w};
            v2f w1a = {w1.x, w1.y}, w1b = {w1.z, w1.w};
            acc[2*ob]   = __builtin_elementwise_fma(ha2, w0a, acc[2*ob]);
            acc[2*ob+1] = __builtin_elementwise_fma(ha2, w0b, acc[2*ob+1]);
            acc[2*ob]   = __builtin_elementwise_fma(hb2, w1a, acc[2*ob]);
            acc[2*ob+1] = __builtin_elementwise_fma(hb2, w1b, acc[2*ob+1]);
        }
    }
    #pragma unroll
    for (int j = 0; j < 10; ++j) H[j] = acc[j];
}

// ws slots
enum { S_PX=0, S_PY, S_PXX, S_PXY, S_PYY, S_PXXX, S_PXXY, S_PXYY, S_PYYY, S_P, S_GPX, S_GPY };

// ---------------- JK1: full 2D 3rd-order jet {v,x,y,xx,xy,yy,xxx,xxy,xyy,yyy}
__global__ __launch_bounds__(256, 2) void pinn_jet_xy(
    const float* __restrict__ x, const float* __restrict__ y, const float* __restrict__ t,
    const float* __restrict__ Win, const float* __restrict__ bin,
    const float* __restrict__ Wh,  const float* __restrict__ bh,
    const float* __restrict__ Wout,const float* __restrict__ bout,
    float* __restrict__ ws)
{
    __shared__ __align__(16) float smem[LDS_TOT];
    stage_weights(smem, Win, bin, Wh, bh, Wout, bout);

    const int pt = blockIdx.x * 256 + threadIdx.x;
    const float xv = x[pt], yv = y[pt], tv = t[pt];
    const v2f xv2 = {xv, xv}, yv2 = {yv, yv}, tv2 = {tv, tv};

    v2f h0[10], hx[10], hy[10], hxx[10], hxy[10], hyy[10],
        h3x[10], hxxy[10], hxyy[10], h3y[10];

    // input layer (pre-act is linear: higher-order pre-act derivs are 0)
    #pragma unroll
    for (int j = 0; j < 10; ++j) {
        v2f w0 = *(const v2f*)&smem[OFF_WIN + 2*j];
        v2f w1 = *(const v2f*)&smem[OFF_WIN + HID + 2*j];
        v2f w2 = *(const v2f*)&smem[OFF_WIN + 2*HID + 2*j];
        v2f av = *(const v2f*)&smem[OFF_BIN + 2*j];
        av = __builtin_elementwise_fma(xv2, w0, av);
        av = __builtin_elementwise_fma(yv2, w1, av);
        av = __builtin_elementwise_fma(tv2, w2, av);
        v2f s  = tanh2(av);
        v2f s2 = s * s;
        v2f s1 = 1.0f - s2;
        v2f f2 = -2.0f * s * s1;
        v2f f3 = s1 * (4.0f * s2 - 2.0f * s1);
        h0[j] = s;
        hx[j] = s1 * w0;  hy[j] = s1 * w1;
        hxx[j] = f2 * w0 * w0;  hxy[j] = f2 * w0 * w1;  hyy[j] = f2 * w1 * w1;
        h3x[j]  = f3 * w0 * w0 * w0;
        hxxy[j] = f3 * w0 * w0 * w1;
        hxyy[j] = f3 * w0 * w1 * w1;
        h3y[j]  = f3 * w1 * w1 * w1;
    }

    #pragma unroll 1
    for (int l = 0; l < NLAY; ++l) {
        const float* Wl = &smem[OFF_WH + l * (HID * HID)];
        const float* bl = &smem[OFF_BH + l * HID];
        matvec<true >(h0,  Wl, bl);
        matvec<false>(hx,  Wl, bl);
        matvec<false>(hy,  Wl, bl);
        matvec<false>(hxx, Wl, bl);
        matvec<false>(hxy, Wl, bl);
        matvec<false>(hyy, Wl, bl);
        matvec<false>(h3x, Wl, bl);
        matvec<false>(hxxy,Wl, bl);
        matvec<false>(hxyy,Wl, bl);
        matvec<false>(h3y, Wl, bl);
        // nonlinear mixing (Faa di Bruno), in place per neuron-pair
        #pragma unroll
        for (int j = 0; j < 10; ++j) {
            v2f a0 = h0[j], ax = hx[j], ay = hy[j];
            v2f axx = hxx[j], axy = hxy[j], ayy = hyy[j];
            v2f a3x = h3x[j], a2xy = hxxy[j], ax2y = hxyy[j], a3y = h3y[j];
            v2f s  = tanh2(a0);
            v2f s2 = s * s;
            v2f s1 = 1.0f - s2;
            v2f f2 = -2.0f * s * s1;
            v2f f3 = s1 * (4.0f * s2 - 2.0f * s1);
            v2f f23 = 3.0f * f2;
            h0[j] = s;
            hx[j] = s1 * ax;  hy[j] = s1 * ay;
            hxx[j] = f2 * ax * ax + s1 * axx;
            hxy[j] = f2 * ax * ay + s1 * axy;
            hyy[j] = f2 * ay * ay + s1 * ayy;
            h3x[j]  = f3 * ax * ax * ax + f23 * ax * axx + s1 * a3x;
            hxxy[j] = f3 * ax * ax * ay + f2 * (axx * ay + 2.0f * ax * axy) + s1 * a2xy;
            hxyy[j] = f3 * ax * ay * ay + f2 * (ayy * ax + 2.0f * ay * axy) + s1 * ax2y;
            h3y[j]  = f3 * ay * ay * ay + f23 * ay * ayy + s1 * a3y;
        }
    }

    // output layer: col0 -> psi derivatives, col1 -> p, p_x, p_y
    v2f dX={0,0}, dY={0,0}, dXX={0,0}, dXY={0,0}, dYY={0,0},
        d3X={0,0}, dXXY={0,0}, dXYY={0,0}, d3Y={0,0},
        dP={0,0}, dPX={0,0}, dPY={0,0};
    #pragma unroll
    for (int j = 0; j < 10; ++j) {
        v2f w0j = {smem[OFF_WOUT + 4*j],     smem[OFF_WOUT + 4*j + 2]};
        v2f w1j = {smem[OFF_WOUT + 4*j + 1], smem[OFF_WOUT + 4*j + 3]};
        dX  = __builtin_elementwise_fma(hx[j],  w0j, dX);
        dY  = __builtin_elementwise_fma(hy[j],  w0j, dY);
        dXX = __builtin_elementwise_fma(hxx[j], w0j, dXX);
        dXY = __builtin_elementwise_fma(hxy[j], w0j, dXY);
        dYY = __builtin_elementwise_fma(hyy[j], w0j, dYY);
        d3X  = __builtin_elementwise_fma(h3x[j],  w0j, d3X);
        dXXY = __builtin_elementwise_fma(hxxy[j], w0j, dXXY);
        dXYY = __builtin_elementwise_fma(hxyy[j], w0j, dXYY);
        d3Y  = __builtin_elementwise_fma(h3y[j],  w0j, d3Y);
        dP  = __builtin_elementwise_fma(h0[j], w1j, dP);
        dPX = __builtin_elementwise_fma(hx[j], w1j, dPX);
        dPY = __builtin_elementwise_fma(hy[j], w1j, dPY);
    }
    ws[S_PX  *BN+pt] = dX.x  + dX.y;
    ws[S_PY  *BN+pt] = dY.x  + dY.y;
    ws[S_PXX *BN+pt] = dXX.x + dXX.y;
    ws[S_PXY *BN+pt] = dXY.x + dXY.y;
    ws[S_PYY *BN+pt] = dYY.x + dYY.y;
    ws[S_PXXX*BN+pt] = d3X.x + d3X.y;
    ws[S_PXXY*BN+pt] = dXXY.x+ dXXY.y;
    ws[S_PXYY*BN+pt] = dXYY.x+ dXYY.y;
    ws[S_PYYY*BN+pt] = d3Y.x + d3Y.y;
    ws[S_P   *BN+pt] = smem[OFF_BOUT + 1] + dP.x + dP.y;
    ws[S_GPX *BN+pt] = dPX.x + dPX.y;
    ws[S_GPY *BN+pt] = dPY.x + dPY.y;
}

// ---------------- JK2: t-mixed 2nd-order jet {v,x,y,t,xt,yt} + fused combine/loss
__global__ __launch_bounds__(256, 2) void pinn_jet_t_combine(
    const float* __restrict__ x, const float* __restrict__ y, const float* __restrict__ t,
    const float* __restrict__ u, const float* __restrict__ v,
    const float* __restrict__ Win, const float* __restrict__ bin,
    const float* __restrict__ Wh,  const float* __restrict__ bh,
    const float* __restrict__ Wout,const float* __restrict__ bout,
    const float* __restrict__ lam1p, const float* __restrict__ lam2p,
    const float* __restrict__ ws, float* __restrict__ out)
{
    __shared__ __align__(16) float smem[LDS_TOT];
    __shared__ float wsum[4];
    stage_weights(smem, Win, bin, Wh, bh, Wout, bout);

    const int tid = threadIdx.x;
    const int pt  = blockIdx.x * 256 + tid;
    const float xv = x[pt], yv = y[pt], tv = t[pt];
    const v2f xv2 = {xv, xv}, yv2 = {yv, yv}, tv2 = {tv, tv};

    v2f g0[10], gx[10], gy[10], gt[10], gxt[10], gyt[10];

    #pragma unroll
    for (int j = 0; j < 10; ++j) {
        v2f w0 = *(const v2f*)&smem[OFF_WIN + 2*j];
        v2f w1 = *(const v2f*)&smem[OFF_WIN + HID + 2*j];
        v2f w2 = *(const v2f*)&smem[OFF_WIN + 2*HID + 2*j];
        v2f av = *(const v2f*)&smem[OFF_BIN + 2*j];
        av = __builtin_elementwise_fma(xv2, w0, av);
        av = __builtin_elementwise_fma(yv2, w1, av);
        av = __builtin_elementwise_fma(tv2, w2, av);
        v2f s  = tanh2(av);
        v2f s1 = 1.0f - s * s;
        v2f f2 = -2.0f * s * s1;
        g0[j] = s;
        gx[j] = s1 * w0;  gy[j] = s1 * w1;  gt[j] = s1 * w2;
        gxt[j] = f2 * w0 * w2;
        gyt[j] = f2 * w1 * w2;
    }

    #pragma unroll 1
    for (int l = 0; l < NLAY; ++l) {
        const float* Wl = &smem[OFF_WH + l * (HID * HID)];
        const float* bl = &smem[OFF_BH + l * HID];
        matvec<true >(g0,  Wl, bl);
        matvec<false>(gx,  Wl, bl);
        matvec<false>(gy,  Wl, bl);
        matvec<false>(gt,  Wl, bl);
        matvec<false>(gxt, Wl, bl);
        matvec<false>(gyt, Wl, bl);
        #pragma unroll
        for (int j = 0; j < 10; ++j) {
            v2f a0 = g0[j], ax = gx[j], ay = gy[j], at = gt[j];
            v2f axt = gxt[j], ayt = gyt[j];
            v2f s  = tanh2(a0);
            v2f s1 = 1.0f - s * s;
            v2f f2 = -2.0f * s * s1;
            g0[j] = s;
            gx[j] = s1 * ax;  gy[j] = s1 * ay;  gt[j] = s1 * at;
            gxt[j] = f2 * ax * at + s1 * axt;
            gyt[j] = f2 * ay * at + s1 * ayt;
        }
    }

    v2f dXT = {0,0}, dYT = {0,0};
    #pragma unroll
    for (int j = 0; j < 10; ++j) {
        v2f w0j = {smem[OFF_WOUT + 4*j], smem[OFF_WOUT + 4*j + 2]};
        dXT = __builtin_elementwise_fma(gxt[j], w0j, dXT);
        dYT = __builtin_elementwise_fma(gyt[j], w0j, dYT);
    }
    const float psi_xt = dXT.x + dXT.y;
    const float psi_yt = dYT.x + dYT.y;

    // ---- fused combine + loss
    const float psi_x   = ws[S_PX  *BN+pt];
    const float psi_y   = ws[S_PY  *BN+pt];
    const float psi_xx  = ws[S_PXX *BN+pt];
    const float psi_xy  = ws[S_PXY *BN+pt];
    const float psi_yy  = ws[S_PYY *BN+pt];
    const float psi_xxx = ws[S_PXXX*BN+pt];
    const float psi_xxy = ws[S_PXXY*BN+pt];
    const float psi_xyy = ws[S_PXYY*BN+pt];
    const float psi_yyy = ws[S_PYYY*BN+pt];
    const float pv      = ws[S_P   *BN+pt];
    const float p_x     = ws[S_GPX *BN+pt];
    const float p_y     = ws[S_GPY *BN+pt];

    const float u_pred = psi_y;
    const float v_pred = -psi_x;
    const float u_x = psi_xy,  u_y = psi_yy,  u_t = psi_yt;
    const float v_x = -psi_xx, v_y = -psi_xy, v_t = -psi_xt;
    const float u_xx = psi_xxy, u_yy = psi_yyy;
    const float v_xx = -psi_xxx, v_yy = -psi_xyy;

    const float lam1 = lam1p[0];
    const float lam2 = lam2p[0];

    const float f_u = lam1 * (u_t + u_pred * u_x + v_pred * u_y) + p_x - lam2 * (u_xx + u_yy);
    const float f_v = lam1 * (v_t + u_pred * v_x + v_pred * v_y) - lam1 * 9.81f + p_y
                      - lam2 * (v_xx + v_yy);

    out[3*pt+0] = pv;
    out[3*pt+1] = u_pred;
    out[3*pt+2] = v_pred;

    const float du = u[pt] - u_pred;
    const float dv = v[pt] - v_pred;
    float term = du * du + dv * dv + f_u * f_u + f_v * f_v;

    #pragma unroll
    for (int off = 32; off > 0; off >>= 1) term += __shfl_down(term, off);
    const int lane = tid & 63, wid = tid >> 6;
    if (lane == 0) wsum[wid] = term;
    __syncthreads();
    if (tid == 0) atomicAdd(&out[3*BN], wsum[0] + wsum[1] + wsum[2] + wsum[3]);
}

extern "C" void kernel_launch(void* const* d_in, const int* in_sizes, int n_in,
                              void* d_out, int out_size, void* d_ws, size_t ws_size,
                              hipStream_t stream) {
    const float* x    = (const float*)d_in[0];
    const float* y    = (const float*)d_in[1];
    const float* t    = (const float*)d_in[2];
    const float* u    = (const float*)d_in[3];
    const float* v    = (const float*)d_in[4];
    const float* Win  = (const float*)d_in[5];
    const float* bin  = (const float*)d_in[6];
    const float* Wh   = (const float*)d_in[7];
    const float* bh   = (const float*)d_in[8];
    const float* Wout = (const float*)d_in[9];
    const float* bout = (const float*)d_in[10];
    const float* lam1 = (const float*)d_in[11];
    const float* lam2 = (const float*)d_in[12];

    float* out = (float*)d_out;
    float* ws  = (float*)d_ws;

    hipMemsetAsync(out + 3 * BN, 0, sizeof(float), stream);

    pinn_jet_xy<<<BN / 256, 256, 0, stream>>>(x, y, t, Win, bin, Wh, bh, Wout, bout, ws);
    pinn_jet_t_combine<<<BN / 256, 256, 0, stream>>>(x, y, t, u, v, Win, bin, Wh, bh,
                                                     Wout, bout, lam1, lam2, ws, out);
}

// Round 3
// 257.440 us; speedup vs baseline: 2.2958x; 2.2958x over previous
//
#include <hip/hip_runtime.h>

typedef float v2f __attribute__((ext_vector_type(2)));

constexpr int BN   = 131072;   // points
constexpr int HID  = 20;       // hidden width
constexpr int NLAY = 7;        // hidden->hidden layers

// LDS layout (floats)
constexpr int OFF_WH   = 0;      // 7*20*20 = 2800
constexpr int OFF_BH   = 2800;   // 7*20    = 140
constexpr int OFF_WIN  = 2940;   // 3*20    = 60
constexpr int OFF_BIN  = 3000;   // 20
constexpr int OFF_WOUT = 3020;   // 20*2    = 40
constexpr int OFF_BOUT = 3060;   // 2
constexpr int LDS_TOT  = 3064;

// ws slots
enum { S_PX = 0, S_PXX, S_PXXX, S_P, S_GPX,
       S_PY, S_PYY, S_PYYY, S_GPY,
       S_D2P, S_D3P, S_D3M, NSLOT };

__device__ __forceinline__ float fast_tanh(float a) {
    float e = __builtin_amdgcn_exp2f(a * 2.8853900817779268f);
    float r = __builtin_amdgcn_rcpf(e + 1.0f);
    return __builtin_fmaf(-2.0f, r, 1.0f);
}
__device__ __forceinline__ v2f tanh2(v2f a) {
    v2f r; r.x = fast_tanh(a.x); r.y = fast_tanh(a.y); return r;
}

__device__ __forceinline__ void stage_weights(
    float* smem, const float* Win, const float* bin, const float* Wh,
    const float* bh, const float* Wout, const float* bout)
{
    const int tid = threadIdx.x;
    for (int i = tid; i < 2800; i += 256) smem[OFF_WH + i] = Wh[i];
    for (int i = tid; i < 140;  i += 256) smem[OFF_BH + i] = bh[i];
    if (tid < 60) smem[OFF_WIN  + tid] = Win[tid];
    if (tid < 20) smem[OFF_BIN  + tid] = bin[tid];
    if (tid < 40) smem[OFF_WOUT + tid] = Wout[tid];
    if (tid < 2)  smem[OFF_BOUT + tid] = bout[tid];
    __syncthreads();
}

// In-place channel matvec: H (10 x v2f = 20 neurons) <- W^T H (+ bias).
template<bool BIASED>
__device__ __forceinline__ void matvec(v2f (&H)[10], const float* __restrict__ Wl,
                                       const float* __restrict__ bl)
{
    v2f acc[10];
    #pragma unroll
    for (int j = 0; j < 10; ++j) {
        if (BIASED) acc[j] = *(const v2f*)&bl[2 * j];
        else        { acc[j].x = 0.f; acc[j].y = 0.f; }
    }
    #pragma unroll
    for (int j = 0; j < 10; ++j) {          // input-neuron pair (2j, 2j+1)
        const float ha = H[j].x, hb = H[j].y;
        const v2f ha2 = {ha, ha}, hb2 = {hb, hb};
        const float* r0 = &Wl[(2 * j) * HID];
        const float* r1 = &Wl[(2 * j + 1) * HID];
        #pragma unroll
        for (int ob = 0; ob < 5; ++ob) {
            float4 w0 = *(const float4*)&r0[4 * ob];
            float4 w1 = *(const float4*)&r1[4 * ob];
            v2f w0a = {w0.x, w0.y}, w0b = {w0.z, w0.w};
            v2f w1a = {w1.x, w1.y}, w1b = {w1.z, w1.w};
            acc[2*ob]   = __builtin_elementwise_fma(ha2, w0a, acc[2*ob]);
            acc[2*ob+1] = __builtin_elementwise_fma(ha2, w0b, acc[2*ob+1]);
            acc[2*ob]   = __builtin_elementwise_fma(hb2, w1a, acc[2*ob]);
            acc[2*ob+1] = __builtin_elementwise_fma(hb2, w1b, acc[2*ob+1]);
        }
    }
    #pragma unroll
    for (int j = 0; j < 10; ++j) H[j] = acc[j];
}

// ---------------- univariate 3rd-order jets along (dx,dy,0), 4 channels
__global__ __launch_bounds__(256, 2) void pinn_jet3(
    const float* __restrict__ x, const float* __restrict__ y, const float* __restrict__ t,
    const float* __restrict__ Win, const float* __restrict__ bin,
    const float* __restrict__ Wh,  const float* __restrict__ bh,
    const float* __restrict__ Wout,const float* __restrict__ bout,
    float* __restrict__ ws)
{
    __shared__ __align__(16) float smem[LDS_TOT];
    stage_weights(smem, Win, bin, Wh, bh, Wout, bout);

    const int pt  = blockIdx.x * 256 + threadIdx.x;
    const int jet = blockIdx.y;
    const float DX[4] = {1.f, 0.f, 1.f,  1.f};
    const float DY[4] = {0.f, 1.f, 1.f, -1.f};
    const float dx = DX[jet], dy = DY[jet];
    const v2f dx2 = {dx, dx}, dy2 = {dy, dy};

    const float xv = x[pt], yv = y[pt], tv = t[pt];
    const v2f xv2 = {xv, xv}, yv2 = {yv, yv}, tv2 = {tv, tv};

    v2f V[10], D1[10], D2[10], D3[10];

    #pragma unroll
    for (int j = 0; j < 10; ++j) {
        v2f w0 = *(const v2f*)&smem[OFF_WIN + 2*j];
        v2f w1 = *(const v2f*)&smem[OFF_WIN + HID + 2*j];
        v2f w2 = *(const v2f*)&smem[OFF_WIN + 2*HID + 2*j];
        v2f av = *(const v2f*)&smem[OFF_BIN + 2*j];
        av = __builtin_elementwise_fma(xv2, w0, av);
        av = __builtin_elementwise_fma(yv2, w1, av);
        av = __builtin_elementwise_fma(tv2, w2, av);
        v2f a1 = dx2 * w0;
        a1 = __builtin_elementwise_fma(dy2, w1, a1);
        v2f s  = tanh2(av);
        v2f s2 = s * s;
        v2f s1 = 1.0f - s2;
        v2f f2 = -2.0f * s * s1;
        v2f f3 = s1 * (4.0f * s2 - 2.0f * s1);
        v2f a1sq = a1 * a1;
        V[j]  = s;
        D1[j] = s1 * a1;
        D2[j] = f2 * a1sq;
        D3[j] = f3 * a1sq * a1;
    }

    #pragma unroll 1
    for (int l = 0; l < NLAY; ++l) {
        const float* Wl = &smem[OFF_WH + l * (HID * HID)];
        const float* bl = &smem[OFF_BH + l * HID];
        matvec<true >(V,  Wl, bl);
        matvec<false>(D1, Wl, bl);
        matvec<false>(D2, Wl, bl);
        matvec<false>(D3, Wl, bl);
        #pragma unroll
        for (int j = 0; j < 10; ++j) {
            v2f a0 = V[j], a1 = D1[j], a2 = D2[j], a3 = D3[j];
            v2f s  = tanh2(a0);
            v2f s2 = s * s;
            v2f s1 = 1.0f - s2;
            v2f f2 = -2.0f * s * s1;
            v2f f3 = s1 * (4.0f * s2 - 2.0f * s1);
            v2f a1sq = a1 * a1;
            V[j]  = s;
            D1[j] = s1 * a1;
            D2[j] = s1 * a2 + f2 * a1sq;
            D3[j] = s1 * a3 + 3.0f * f2 * (a1 * a2) + f3 * a1sq * a1;
        }
    }

    v2f d1 = {0,0}, d2 = {0,0}, d3 = {0,0}, dP = {0,0}, dP1 = {0,0};
    #pragma unroll
    for (int j = 0; j < 10; ++j) {
        v2f w0j = {smem[OFF_WOUT + 4*j],     smem[OFF_WOUT + 4*j + 2]};
        v2f w1j = {smem[OFF_WOUT + 4*j + 1], smem[OFF_WOUT + 4*j + 3]};
        d1  = __builtin_elementwise_fma(D1[j], w0j, d1);
        d2  = __builtin_elementwise_fma(D2[j], w0j, d2);
        d3  = __builtin_elementwise_fma(D3[j], w0j, d3);
        dP  = __builtin_elementwise_fma(V[j],  w1j, dP);
        dP1 = __builtin_elementwise_fma(D1[j], w1j, dP1);
    }
    const float r1 = d1.x + d1.y;
    const float r2 = d2.x + d2.y;
    const float r3 = d3.x + d3.y;

    switch (jet) {
        case 0:
            ws[S_PX  *BN+pt] = r1;
            ws[S_PXX *BN+pt] = r2;
            ws[S_PXXX*BN+pt] = r3;
            ws[S_P   *BN+pt] = smem[OFF_BOUT + 1] + dP.x + dP.y;
            ws[S_GPX *BN+pt] = dP1.x + dP1.y;
            break;
        case 1:
            ws[S_PY  *BN+pt] = r1;
            ws[S_PYY *BN+pt] = r2;
            ws[S_PYYY*BN+pt] = r3;
            ws[S_GPY *BN+pt] = dP1.x + dP1.y;
            break;
        case 2:
            ws[S_D2P *BN+pt] = r2;
            ws[S_D3P *BN+pt] = r3;
            break;
        case 3:
            ws[S_D3M *BN+pt] = r3;
            break;
    }
}

// ---------------- t-mixed 2nd-order jet {v,x,y,t,xt,yt} + fused combine/loss
__global__ __launch_bounds__(256, 2) void pinn_jet_t_combine(
    const float* __restrict__ x, const float* __restrict__ y, const float* __restrict__ t,
    const float* __restrict__ u, const float* __restrict__ v,
    const float* __restrict__ Win, const float* __restrict__ bin,
    const float* __restrict__ Wh,  const float* __restrict__ bh,
    const float* __restrict__ Wout,const float* __restrict__ bout,
    const float* __restrict__ lam1p, const float* __restrict__ lam2p,
    const float* __restrict__ ws, float* __restrict__ out)
{
    __shared__ __align__(16) float smem[LDS_TOT];
    __shared__ float wsum[4];
    stage_weights(smem, Win, bin, Wh, bh, Wout, bout);

    const int tid = threadIdx.x;
    const int pt  = blockIdx.x * 256 + tid;
    const float xv = x[pt], yv = y[pt], tv = t[pt];
    const v2f xv2 = {xv, xv}, yv2 = {yv, yv}, tv2 = {tv, tv};

    v2f g0[10], gx[10], gy[10], gt[10], gxt[10], gyt[10];

    #pragma unroll
    for (int j = 0; j < 10; ++j) {
        v2f w0 = *(const v2f*)&smem[OFF_WIN + 2*j];
        v2f w1 = *(const v2f*)&smem[OFF_WIN + HID + 2*j];
        v2f w2 = *(const v2f*)&smem[OFF_WIN + 2*HID + 2*j];
        v2f av = *(const v2f*)&smem[OFF_BIN + 2*j];
        av = __builtin_elementwise_fma(xv2, w0, av);
        av = __builtin_elementwise_fma(yv2, w1, av);
        av = __builtin_elementwise_fma(tv2, w2, av);
        v2f s  = tanh2(av);
        v2f s1 = 1.0f - s * s;
        v2f f2 = -2.0f * s * s1;
        g0[j] = s;
        gx[j] = s1 * w0;  gy[j] = s1 * w1;  gt[j] = s1 * w2;
        gxt[j] = f2 * w0 * w2;
        gyt[j] = f2 * w1 * w2;
    }

    #pragma unroll 1
    for (int l = 0; l < NLAY; ++l) {
        const float* Wl = &smem[OFF_WH + l * (HID * HID)];
        const float* bl = &smem[OFF_BH + l * HID];
        matvec<true >(g0,  Wl, bl);
        matvec<false>(gx,  Wl, bl);
        matvec<false>(gy,  Wl, bl);
        matvec<false>(gt,  Wl, bl);
        matvec<false>(gxt, Wl, bl);
        matvec<false>(gyt, Wl, bl);
        #pragma unroll
        for (int j = 0; j < 10; ++j) {
            v2f a0 = g0[j], ax = gx[j], ay = gy[j], at = gt[j];
            v2f axt = gxt[j], ayt = gyt[j];
            v2f s  = tanh2(a0);
            v2f s1 = 1.0f - s * s;
            v2f f2 = -2.0f * s * s1;
            g0[j] = s;
            gx[j] = s1 * ax;  gy[j] = s1 * ay;  gt[j] = s1 * at;
            gxt[j] = f2 * ax * at + s1 * axt;
            gyt[j] = f2 * ay * at + s1 * ayt;
        }
    }

    v2f dXT = {0,0}, dYT = {0,0};
    #pragma unroll
    for (int j = 0; j < 10; ++j) {
        v2f w0j = {smem[OFF_WOUT + 4*j], smem[OFF_WOUT + 4*j + 2]};
        dXT = __builtin_elementwise_fma(gxt[j], w0j, dXT);
        dYT = __builtin_elementwise_fma(gyt[j], w0j, dYT);
    }
    const float psi_xt = dXT.x + dXT.y;
    const float psi_yt = dYT.x + dYT.y;

    // ---- fused combine + loss (polarization for mixed x/y derivatives)
    const float psi_x   = ws[S_PX  *BN+pt];
    const float psi_xx  = ws[S_PXX *BN+pt];
    const float psi_xxx = ws[S_PXXX*BN+pt];
    const float pv      = ws[S_P   *BN+pt];
    const float p_x     = ws[S_GPX *BN+pt];
    const float psi_y   = ws[S_PY  *BN+pt];
    const float psi_yy  = ws[S_PYY *BN+pt];
    const float psi_yyy = ws[S_PYYY*BN+pt];
    const float p_y     = ws[S_GPY *BN+pt];
    const float d2p     = ws[S_D2P *BN+pt];
    const float d3p     = ws[S_D3P *BN+pt];
    const float d3m     = ws[S_D3M *BN+pt];

    const float psi_xy  = 0.5f * (d2p - psi_xx - psi_yy);
    const float psi_xxy = (d3p - d3m - 2.0f * psi_yyy) * (1.0f / 6.0f);
    const float psi_xyy = (d3p + d3m - 2.0f * psi_xxx) * (1.0f / 6.0f);

    const float u_pred = psi_y;
    const float v_pred = -psi_x;
    const float u_x = psi_xy,  u_y = psi_yy,  u_t = psi_yt;
    const float v_x = -psi_xx, v_y = -psi_xy, v_t = -psi_xt;
    const float u_xx = psi_xxy, u_yy = psi_yyy;
    const float v_xx = -psi_xxx, v_yy = -psi_xyy;

    const float lam1 = lam1p[0];
    const float lam2 = lam2p[0];

    const float f_u = lam1 * (u_t + u_pred * u_x + v_pred * u_y) + p_x - lam2 * (u_xx + u_yy);
    const float f_v = lam1 * (v_t + u_pred * v_x + v_pred * v_y) - lam1 * 9.81f + p_y
                      - lam2 * (v_xx + v_yy);

    out[3*pt+0] = pv;
    out[3*pt+1] = u_pred;
    out[3*pt+2] = v_pred;

    const float du = u[pt] - u_pred;
    const float dv = v[pt] - v_pred;
    float term = du * du + dv * dv + f_u * f_u + f_v * f_v;

    #pragma unroll
    for (int off = 32; off > 0; off >>= 1) term += __shfl_down(term, off);
    const int lane = tid & 63, wid = tid >> 6;
    if (lane == 0) wsum[wid] = term;
    __syncthreads();
    if (tid == 0) atomicAdd(&out[3*BN], wsum[0] + wsum[1] + wsum[2] + wsum[3]);
}

extern "C" void kernel_launch(void* const* d_in, const int* in_sizes, int n_in,
                              void* d_out, int out_size, void* d_ws, size_t ws_size,
                              hipStream_t stream) {
    const float* x    = (const float*)d_in[0];
    const float* y    = (const float*)d_in[1];
    const float* t    = (const float*)d_in[2];
    const float* u    = (const float*)d_in[3];
    const float* v    = (const float*)d_in[4];
    const float* Win  = (const float*)d_in[5];
    const float* bin  = (const float*)d_in[6];
    const float* Wh   = (const float*)d_in[7];
    const float* bh   = (const float*)d_in[8];
    const float* Wout = (const float*)d_in[9];
    const float* bout = (const float*)d_in[10];
    const float* lam1 = (const float*)d_in[11];
    const float* lam2 = (const float*)d_in[12];

    float* out = (float*)d_out;
    float* ws  = (float*)d_ws;

    hipMemsetAsync(out + 3 * BN, 0, sizeof(float), stream);

    pinn_jet3<<<dim3(BN / 256, 4), 256, 0, stream>>>(x, y, t, Win, bin, Wh, bh,
                                                     Wout, bout, ws);
    pinn_jet_t_combine<<<BN / 256, 256, 0, stream>>>(x, y, t, u, v, Win, bin, Wh, bh,
                                                     Wout, bout, lam1, lam2, ws, out);
}

// Round 4
// 239.557 us; speedup vs baseline: 2.4672x; 1.0746x over previous
//
#include <hip/hip_runtime.h>

typedef float v2f __attribute__((ext_vector_type(2)));

constexpr int BN   = 131072;   // points
constexpr int HID  = 20;       // hidden width
constexpr int NLAY = 7;        // hidden->hidden layers

// LDS layout (floats)
constexpr int OFF_WH   = 0;      // 7*20*20 = 2800
constexpr int OFF_BH   = 2800;   // 7*20    = 140
constexpr int OFF_WIN  = 2940;   // 3*20    = 60
constexpr int OFF_BIN  = 3000;   // 20
constexpr int OFF_WOUT = 3020;   // 20*2    = 40
constexpr int OFF_BOUT = 3060;   // 2
constexpr int LDS_TOT  = 3064;

// ws slots
enum { S_PX = 0, S_PXX, S_PXXX, S_P, S_GPX,
       S_PY, S_PYY, S_PYYY, S_GPY,
       S_D2P, S_D3P, S_D3M, S_XT, S_YT, NSLOT };

__device__ __forceinline__ float fast_tanh(float a) {
    float e = __builtin_amdgcn_exp2f(a * 2.8853900817779268f);
    float r = __builtin_amdgcn_rcpf(e + 1.0f);
    return __builtin_fmaf(-2.0f, r, 1.0f);
}
__device__ __forceinline__ v2f tanh2(v2f a) {
    v2f r; r.x = fast_tanh(a.x); r.y = fast_tanh(a.y); return r;
}

__device__ __forceinline__ void stage_weights(
    float* smem, const float* Win, const float* bin, const float* Wh,
    const float* bh, const float* Wout, const float* bout)
{
    const int tid = threadIdx.x;
    for (int i = tid; i < 2800; i += 256) smem[OFF_WH + i] = Wh[i];
    for (int i = tid; i < 140;  i += 256) smem[OFF_BH + i] = bh[i];
    if (tid < 60) smem[OFF_WIN  + tid] = Win[tid];
    if (tid < 20) smem[OFF_BIN  + tid] = bin[tid];
    if (tid < 40) smem[OFF_WOUT + tid] = Wout[tid];
    if (tid < 2)  smem[OFF_BOUT + tid] = bout[tid];
    __syncthreads();
}

#define FMA2(a, b, c) __builtin_elementwise_fma((a), (b), (c))
__device__ __forceinline__ v2f splat(float s) { v2f r = {s, s}; return r; }

// ---------------------------------------------------------------- K1
__global__ __launch_bounds__(256)
__attribute__((amdgpu_waves_per_eu(2, 2)))
void pinn_jets(
    const float* __restrict__ x, const float* __restrict__ y, const float* __restrict__ t,
    const float* __restrict__ Win, const float* __restrict__ bin,
    const float* __restrict__ Wh,  const float* __restrict__ bh,
    const float* __restrict__ Wout,const float* __restrict__ bout,
    float* __restrict__ ws)
{
    __shared__ __align__(16) float smem[LDS_TOT];
    stage_weights(smem, Win, bin, Wh, bh, Wout, bout);

    const int pt    = blockIdx.x * 256 + threadIdx.x;
    const int slice = blockIdx.y;

    const float xv = x[pt], yv = y[pt], tv = t[pt];
    const v2f xv2 = splat(xv), yv2 = splat(yv), tv2 = splat(tv);

    if (slice < 4) {
        // ---------------- univariate 3rd-order jet along (dx,dy,0)
        const float DXT[4] = {1.f, 0.f, 1.f,  1.f};
        const float DYT[4] = {0.f, 1.f, 1.f, -1.f};
        const v2f dx2 = splat(DXT[slice]), dy2 = splat(DYT[slice]);

        v2f V[10], D1[10], D2[10], D3[10];

        #pragma unroll
        for (int j = 0; j < 10; ++j) {
            v2f w0 = *(const v2f*)&smem[OFF_WIN + 2*j];
            v2f w1 = *(const v2f*)&smem[OFF_WIN + HID + 2*j];
            v2f w2 = *(const v2f*)&smem[OFF_WIN + 2*HID + 2*j];
            v2f av = *(const v2f*)&smem[OFF_BIN + 2*j];
            av = FMA2(xv2, w0, av);
            av = FMA2(yv2, w1, av);
            av = FMA2(tv2, w2, av);
            v2f a1 = dx2 * w0;
            a1 = FMA2(dy2, w1, a1);
            v2f s  = tanh2(av);
            v2f s2 = s * s;
            v2f s1 = 1.0f - s2;
            v2f f2 = -2.0f * s * s1;
            v2f f3 = s1 * (4.0f * s2 - 2.0f * s1);
            v2f a1sq = a1 * a1;
            V[j]  = s;
            D1[j] = s1 * a1;
            D2[j] = f2 * a1sq;
            D3[j] = f3 * a1sq * a1;
        }

        #pragma unroll 1
        for (int l = 0; l < NLAY; ++l) {
            const float* Wl = &smem[OFF_WH + l * (HID * HID)];
            const float* bl = &smem[OFF_BH + l * HID];
            v2f aV[10], a1[10], a2[10], a3[10];
            #pragma unroll
            for (int j = 0; j < 10; ++j) {
                aV[j] = *(const v2f*)&bl[2 * j];
                a1[j] = splat(0.f); a2[j] = splat(0.f); a3[j] = splat(0.f);
            }
            #pragma unroll
            for (int i = 0; i < 10; ++i) {   // input-neuron pair (2i, 2i+1)
                const v2f vA = splat(V[i].x),  vB = splat(V[i].y);
                const v2f dA = splat(D1[i].x), dB = splat(D1[i].y);
                const v2f eA = splat(D2[i].x), eB = splat(D2[i].y);
                const v2f fA = splat(D3[i].x), fB = splat(D3[i].y);
                const float* r0 = &Wl[(2 * i) * HID];
                const float* r1 = &Wl[(2 * i + 1) * HID];
                #pragma unroll
                for (int ob = 0; ob < 5; ++ob) {
                    float4 w0 = *(const float4*)&r0[4 * ob];
                    float4 w1 = *(const float4*)&r1[4 * ob];
                    v2f w0a = {w0.x, w0.y}, w0b = {w0.z, w0.w};
                    v2f w1a = {w1.x, w1.y}, w1b = {w1.z, w1.w};
                    aV[2*ob]   = FMA2(vA, w0a, aV[2*ob]);
                    aV[2*ob]   = FMA2(vB, w1a, aV[2*ob]);
                    aV[2*ob+1] = FMA2(vA, w0b, aV[2*ob+1]);
                    aV[2*ob+1] = FMA2(vB, w1b, aV[2*ob+1]);
                    a1[2*ob]   = FMA2(dA, w0a, a1[2*ob]);
                    a1[2*ob]   = FMA2(dB, w1a, a1[2*ob]);
                    a1[2*ob+1] = FMA2(dA, w0b, a1[2*ob+1]);
                    a1[2*ob+1] = FMA2(dB, w1b, a1[2*ob+1]);
                    a2[2*ob]   = FMA2(eA, w0a, a2[2*ob]);
                    a2[2*ob]   = FMA2(eB, w1a, a2[2*ob]);
                    a2[2*ob+1] = FMA2(eA, w0b, a2[2*ob+1]);
                    a2[2*ob+1] = FMA2(eB, w1b, a2[2*ob+1]);
                    a3[2*ob]   = FMA2(fA, w0a, a3[2*ob]);
                    a3[2*ob]   = FMA2(fB, w1a, a3[2*ob]);
                    a3[2*ob+1] = FMA2(fA, w0b, a3[2*ob+1]);
                    a3[2*ob+1] = FMA2(fB, w1b, a3[2*ob+1]);
                }
            }
            #pragma unroll
            for (int j = 0; j < 10; ++j) {
                v2f s  = tanh2(aV[j]);
                v2f s2 = s * s;
                v2f s1 = 1.0f - s2;
                v2f f2 = -2.0f * s * s1;
                v2f f3 = s1 * (4.0f * s2 - 2.0f * s1);
                v2f u1 = a1[j];
                v2f u1sq = u1 * u1;
                V[j]  = s;
                D1[j] = s1 * u1;
                D2[j] = s1 * a2[j] + f2 * u1sq;
                D3[j] = s1 * a3[j] + 3.0f * f2 * (u1 * a2[j]) + f3 * u1sq * u1;
            }
        }

        v2f d1 = splat(0.f), d2 = splat(0.f), d3 = splat(0.f),
            dP = splat(0.f), dP1 = splat(0.f);
        #pragma unroll
        for (int j = 0; j < 10; ++j) {
            v2f w0j = {smem[OFF_WOUT + 4*j],     smem[OFF_WOUT + 4*j + 2]};
            v2f w1j = {smem[OFF_WOUT + 4*j + 1], smem[OFF_WOUT + 4*j + 3]};
            d1  = FMA2(D1[j], w0j, d1);
            d2  = FMA2(D2[j], w0j, d2);
            d3  = FMA2(D3[j], w0j, d3);
            dP  = FMA2(V[j],  w1j, dP);
            dP1 = FMA2(D1[j], w1j, dP1);
        }
        const float r1 = d1.x + d1.y;
        const float r2 = d2.x + d2.y;
        const float r3 = d3.x + d3.y;

        switch (slice) {
            case 0:
                ws[S_PX  *BN+pt] = r1;
                ws[S_PXX *BN+pt] = r2;
                ws[S_PXXX*BN+pt] = r3;
                ws[S_P   *BN+pt] = smem[OFF_BOUT + 1] + dP.x + dP.y;
                ws[S_GPX *BN+pt] = dP1.x + dP1.y;
                break;
            case 1:
                ws[S_PY  *BN+pt] = r1;
                ws[S_PYY *BN+pt] = r2;
                ws[S_PYYY*BN+pt] = r3;
                ws[S_GPY *BN+pt] = dP1.x + dP1.y;
                break;
            case 2:
                ws[S_D2P *BN+pt] = r2;
                ws[S_D3P *BN+pt] = r3;
                break;
            default:
                ws[S_D3M *BN+pt] = r3;
                break;
        }
    } else {
        // ---------------- t-mixed 2nd-order jet {v,x,y,t,xt,yt}
        v2f G0[10], GX[10], GY[10], GT[10], GXT[10], GYT[10];

        #pragma unroll
        for (int j = 0; j < 10; ++j) {
            v2f w0 = *(const v2f*)&smem[OFF_WIN + 2*j];
            v2f w1 = *(const v2f*)&smem[OFF_WIN + HID + 2*j];
            v2f w2 = *(const v2f*)&smem[OFF_WIN + 2*HID + 2*j];
            v2f av = *(const v2f*)&smem[OFF_BIN + 2*j];
            av = FMA2(xv2, w0, av);
            av = FMA2(yv2, w1, av);
            av = FMA2(tv2, w2, av);
            v2f s  = tanh2(av);
            v2f s1 = 1.0f - s * s;
            v2f f2 = -2.0f * s * s1;
            G0[j] = s;
            GX[j] = s1 * w0;  GY[j] = s1 * w1;  GT[j] = s1 * w2;
            GXT[j] = f2 * w0 * w2;
            GYT[j] = f2 * w1 * w2;
        }

        #pragma unroll 1
        for (int l = 0; l < NLAY; ++l) {
            const float* Wl = &smem[OFF_WH + l * (HID * HID)];
            const float* bl = &smem[OFF_BH + l * HID];
            // pass 1: {G0, GX, GY} -> pre-activations stored back in place
            {
                v2f a0[10], ax[10], ay[10];
                #pragma unroll
                for (int j = 0; j < 10; ++j) {
                    a0[j] = *(const v2f*)&bl[2 * j];
                    ax[j] = splat(0.f); ay[j] = splat(0.f);
                }
                #pragma unroll
                for (int i = 0; i < 10; ++i) {
                    const v2f vA = splat(G0[i].x), vB = splat(G0[i].y);
                    const v2f xA = splat(GX[i].x), xB = splat(GX[i].y);
                    const v2f yA = splat(GY[i].x), yB = splat(GY[i].y);
                    const float* r0 = &Wl[(2 * i) * HID];
                    const float* r1 = &Wl[(2 * i + 1) * HID];
                    #pragma unroll
                    for (int ob = 0; ob < 5; ++ob) {
                        float4 w0 = *(const float4*)&r0[4 * ob];
                        float4 w1 = *(const float4*)&r1[4 * ob];
                        v2f w0a = {w0.x, w0.y}, w0b = {w0.z, w0.w};
                        v2f w1a = {w1.x, w1.y}, w1b = {w1.z, w1.w};
                        a0[2*ob]   = FMA2(vA, w0a, a0[2*ob]);
                        a0[2*ob]   = FMA2(vB, w1a, a0[2*ob]);
                        a0[2*ob+1] = FMA2(vA, w0b, a0[2*ob+1]);
                        a0[2*ob+1] = FMA2(vB, w1b, a0[2*ob+1]);
                        ax[2*ob]   = FMA2(xA, w0a, ax[2*ob]);
                        ax[2*ob]   = FMA2(xB, w1a, ax[2*ob]);
                        ax[2*ob+1] = FMA2(xA, w0b, ax[2*ob+1]);
                        ax[2*ob+1] = FMA2(xB, w1b, ax[2*ob+1]);
                        ay[2*ob]   = FMA2(yA, w0a, ay[2*ob]);
                        ay[2*ob]   = FMA2(yB, w1a, ay[2*ob]);
                        ay[2*ob+1] = FMA2(yA, w0b, ay[2*ob+1]);
                        ay[2*ob+1] = FMA2(yB, w1b, ay[2*ob+1]);
                    }
                }
                #pragma unroll
                for (int j = 0; j < 10; ++j) { G0[j] = a0[j]; GX[j] = ax[j]; GY[j] = ay[j]; }
            }
            // pass 2: {GT, GXT, GYT} -> accumulators, then fused mixing
            {
                v2f at[10], axt[10], ayt[10];
                #pragma unroll
                for (int j = 0; j < 10; ++j) {
                    at[j] = splat(0.f); axt[j] = splat(0.f); ayt[j] = splat(0.f);
                }
                #pragma unroll
                for (int i = 0; i < 10; ++i) {
                    const v2f tA = splat(GT[i].x),  tB = splat(GT[i].y);
                    const v2f pA = splat(GXT[i].x), pB = splat(GXT[i].y);
                    const v2f qA = splat(GYT[i].x), qB = splat(GYT[i].y);
                    const float* r0 = &Wl[(2 * i) * HID];
                    const float* r1 = &Wl[(2 * i + 1) * HID];
                    #pragma unroll
                    for (int ob = 0; ob < 5; ++ob) {
                        float4 w0 = *(const float4*)&r0[4 * ob];
                        float4 w1 = *(const float4*)&r1[4 * ob];
                        v2f w0a = {w0.x, w0.y}, w0b = {w0.z, w0.w};
                        v2f w1a = {w1.x, w1.y}, w1b = {w1.z, w1.w};
                        at[2*ob]    = FMA2(tA, w0a, at[2*ob]);
                        at[2*ob]    = FMA2(tB, w1a, at[2*ob]);
                        at[2*ob+1]  = FMA2(tA, w0b, at[2*ob+1]);
                        at[2*ob+1]  = FMA2(tB, w1b, at[2*ob+1]);
                        axt[2*ob]   = FMA2(pA, w0a, axt[2*ob]);
                        axt[2*ob]   = FMA2(pB, w1a, axt[2*ob]);
                        axt[2*ob+1] = FMA2(pA, w0b, axt[2*ob+1]);
                        axt[2*ob+1] = FMA2(pB, w1b, axt[2*ob+1]);
                        ayt[2*ob]   = FMA2(qA, w0a, ayt[2*ob]);
                        ayt[2*ob]   = FMA2(qB, w1a, ayt[2*ob]);
                        ayt[2*ob+1] = FMA2(qA, w0b, ayt[2*ob+1]);
                        ayt[2*ob+1] = FMA2(qB, w1b, ayt[2*ob+1]);
                    }
                }
                #pragma unroll
                for (int j = 0; j < 10; ++j) {
                    v2f a0 = G0[j], ax = GX[j], ay = GY[j];
                    v2f s  = tanh2(a0);
                    v2f s1 = 1.0f - s * s;
                    v2f f2 = -2.0f * s * s1;
                    G0[j] = s;
                    GX[j] = s1 * ax;  GY[j] = s1 * ay;  GT[j] = s1 * at[j];
                    GXT[j] = f2 * ax * at[j] + s1 * axt[j];
                    GYT[j] = f2 * ay * at[j] + s1 * ayt[j];
                }
            }
        }

        v2f dXT = splat(0.f), dYT = splat(0.f);
        #pragma unroll
        for (int j = 0; j < 10; ++j) {
            v2f w0j = {smem[OFF_WOUT + 4*j], smem[OFF_WOUT + 4*j + 2]};
            dXT = FMA2(GXT[j], w0j, dXT);
            dYT = FMA2(GYT[j], w0j, dYT);
        }
        ws[S_XT*BN+pt] = dXT.x + dXT.y;
        ws[S_YT*BN+pt] = dYT.x + dYT.y;
    }
}

// ---------------------------------------------------------------- K2: combine + loss
__global__ __launch_bounds__(256) void pinn_combine(
    const float* __restrict__ ws,
    const float* __restrict__ u, const float* __restrict__ v,
    const float* __restrict__ lam1p, const float* __restrict__ lam2p,
    float* __restrict__ out)
{
    __shared__ float wsum[4];
    const int tid = threadIdx.x;
    const int pt  = blockIdx.x * 256 + tid;

    const float psi_x   = ws[S_PX  *BN+pt];
    const float psi_xx  = ws[S_PXX *BN+pt];
    const float psi_xxx = ws[S_PXXX*BN+pt];
    const float pv      = ws[S_P   *BN+pt];
    const float p_x     = ws[S_GPX *BN+pt];
    const float psi_y   = ws[S_PY  *BN+pt];
    const float psi_yy  = ws[S_PYY *BN+pt];
    const float psi_yyy = ws[S_PYYY*BN+pt];
    const float p_y     = ws[S_GPY *BN+pt];
    const float d2p     = ws[S_D2P *BN+pt];
    const float d3p     = ws[S_D3P *BN+pt];
    const float d3m     = ws[S_D3M *BN+pt];
    const float psi_xt  = ws[S_XT  *BN+pt];
    const float psi_yt  = ws[S_YT  *BN+pt];

    const float psi_xy  = 0.5f * (d2p - psi_xx - psi_yy);
    const float psi_xxy = (d3p - d3m - 2.0f * psi_yyy) * (1.0f / 6.0f);
    const float psi_xyy = (d3p + d3m - 2.0f * psi_xxx) * (1.0f / 6.0f);

    const float u_pred = psi_y;
    const float v_pred = -psi_x;
    const float u_x = psi_xy,  u_y = psi_yy,  u_t = psi_yt;
    const float v_x = -psi_xx, v_y = -psi_xy, v_t = -psi_xt;
    const float u_xx = psi_xxy, u_yy = psi_yyy;
    const float v_xx = -psi_xxx, v_yy = -psi_xyy;

    const float lam1 = lam1p[0];
    const float lam2 = lam2p[0];

    const float f_u = lam1 * (u_t + u_pred * u_x + v_pred * u_y) + p_x - lam2 * (u_xx + u_yy);
    const float f_v = lam1 * (v_t + u_pred * v_x + v_pred * v_y) - lam1 * 9.81f + p_y
                      - lam2 * (v_xx + v_yy);

    out[3*pt+0] = pv;
    out[3*pt+1] = u_pred;
    out[3*pt+2] = v_pred;

    const float du = u[pt] - u_pred;
    const float dv = v[pt] - v_pred;
    float term = du * du + dv * dv + f_u * f_u + f_v * f_v;

    #pragma unroll
    for (int off = 32; off > 0; off >>= 1) term += __shfl_down(term, off);
    const int lane = tid & 63, wid = tid >> 6;
    if (lane == 0) wsum[wid] = term;
    __syncthreads();
    if (tid == 0) atomicAdd(&out[3*BN], wsum[0] + wsum[1] + wsum[2] + wsum[3]);
}

extern "C" void kernel_launch(void* const* d_in, const int* in_sizes, int n_in,
                              void* d_out, int out_size, void* d_ws, size_t ws_size,
                              hipStream_t stream) {
    const float* x    = (const float*)d_in[0];
    const float* y    = (const float*)d_in[1];
    const float* t    = (const float*)d_in[2];
    const float* u    = (const float*)d_in[3];
    const float* v    = (const float*)d_in[4];
    const float* Win  = (const float*)d_in[5];
    const float* bin  = (const float*)d_in[6];
    const float* Wh   = (const float*)d_in[7];
    const float* bh   = (const float*)d_in[8];
    const float* Wout = (const float*)d_in[9];
    const float* bout = (const float*)d_in[10];
    const float* lam1 = (const float*)d_in[11];
    const float* lam2 = (const float*)d_in[12];

    float* out = (float*)d_out;
    float* ws  = (float*)d_ws;

    hipMemsetAsync(out + 3 * BN, 0, sizeof(float), stream);

    pinn_jets<<<dim3(BN / 256, 5), 256, 0, stream>>>(x, y, t, Win, bin, Wh, bh,
                                                     Wout, bout, ws);
    pinn_combine<<<BN / 256, 256, 0, stream>>>(ws, u, v, lam1, lam2, out);
}